// Round 11
// baseline (225.004 us; speedup 1.0000x reference)
//
#include <hip/hip_runtime.h>
#include <stdint.h>

typedef __bf16 bf16x8_t __attribute__((ext_vector_type(8)));
typedef float f32x4_t __attribute__((ext_vector_type(4)));

#define AS1 __attribute__((address_space(1)))
#define AS3 __attribute__((address_space(3)))

static __device__ __forceinline__ unsigned short f2bf(float f) {
  union { float f; unsigned u; } a;
  a.f = f;
  unsigned r = a.u + 0x7fffu + ((a.u >> 16) & 1u);
  return (unsigned short)(r >> 16);
}

static __device__ __forceinline__ unsigned pack2bf(float lo, float hi) {
  return (unsigned)f2bf(lo) | ((unsigned)f2bf(hi) << 16);
}

// ---------- 1. fp32 -> bf16 elementwise ----------
__global__ void cvt_bf16_kernel(const float* __restrict__ in, unsigned short* __restrict__ out) {
  long i = ((long)blockIdx.x * blockDim.x + threadIdx.x) * 4;
  float4 v = *(const float4*)(in + i);
  ushort4 o;
  o.x = f2bf(v.x);
  o.y = f2bf(v.y);
  o.z = f2bf(v.z);
  o.w = f2bf(v.w);
  *(ushort4*)(out + i) = o;
}

// ---------- 2. fp32 [R][C] (row stride ld) -> bf16 [C][R] (row stride dld) ----------
__global__ void transpose_f32_bf16(const float* __restrict__ src, unsigned short* __restrict__ dst,
                                   int ld, int dld, long sbs, long dbs) {
  __shared__ float tile[64][65];
  src += (long)blockIdx.z * sbs;
  dst += (long)blockIdx.z * dbs;
  const int c0 = blockIdx.x * 64, r0 = blockIdx.y * 64;
  const int tx = threadIdx.x, ty = threadIdx.y;
#pragma unroll
  for (int j = 0; j < 64; j += 4)
    tile[ty + j][tx] = src[(long)(r0 + ty + j) * ld + (c0 + tx)];
  __syncthreads();
#pragma unroll
  for (int j = 0; j < 64; j += 4)
    dst[(long)(c0 + ty + j) * dld + (r0 + tx)] = f2bf(tile[tx][ty + j]);
}

// ---------- 3. GEMM (round-9 pipeline: 3-buf LDS, counted vmcnt, slot swizzle) ----------
__global__ __launch_bounds__(256) void gemm_bt(const unsigned short* __restrict__ A,
                                               const unsigned short* __restrict__ Bt,
                                               float* __restrict__ C,
                                               int M, int N, int K, int nx) {
  __shared__ unsigned short As[3][128 * 32];
  __shared__ unsigned short Bs[3][128 * 32];
  const int nwg = gridDim.x;
  const int bid = blockIdx.x;
  const int swz = (bid & 7) * (nwg >> 3) + (bid >> 3);  // XCD chunking
  const int by = swz / nx;
  const int bx = swz - by * nx;

  const int tid = threadIdx.x;
  const int wid = tid >> 6, lane = tid & 63;
  const int r16 = lane & 15, g = lane >> 4;
  const long bm = (long)by * 128;
  const long bn = (long)bx * 128;
  const int wr = (wid >> 1) * 64, wc = (wid & 1) * 64;
  const int gr = g ^ (r16 & 3);
  const int sslot = (lane & 3) ^ ((lane >> 2) & 3);

  f32x4_t acc[4][4];
#pragma unroll
  for (int i = 0; i < 4; i++)
#pragma unroll
    for (int j = 0; j < 4; j++) acc[i][j] = (f32x4_t){0.f, 0.f, 0.f, 0.f};

  const int NT = K >> 5;

#define STAGE_G(buf, kt)                                                              \
  {                                                                                   \
    _Pragma("unroll") for (int i = 0; i < 2; i++) {                                   \
      const int chunk = (i * 4 + wid) * 64 + lane;                                    \
      const int row = chunk >> 2;                                                     \
      __builtin_amdgcn_global_load_lds(                                               \
          (const AS1 void*)(A + (bm + row) * K + (kt) + sslot * 8),                   \
          (AS3 void*)(&As[buf][chunk * 8]), 16, 0, 0);                                \
      __builtin_amdgcn_global_load_lds(                                               \
          (const AS1 void*)(Bt + (bn + row) * K + (kt) + sslot * 8),                  \
          (AS3 void*)(&Bs[buf][chunk * 8]), 16, 0, 0);                                \
    }                                                                                 \
  }

  STAGE_G(0, 0)
  STAGE_G(1, 32)
  asm volatile("s_waitcnt vmcnt(4)" ::: "memory");
  __builtin_amdgcn_s_barrier();

  for (int T = 0; T < NT; T++) {
    const int cur = T % 3;
    if (T + 2 < NT) {
      const int nb = (T + 2) % 3;
      STAGE_G(nb, (T + 2) * 32)
    }
    __builtin_amdgcn_sched_barrier(0);
    bf16x8_t af[4], bfr[4];
#pragma unroll
    for (int mi = 0; mi < 4; mi++)
      af[mi] = *(const bf16x8_t*)(&As[cur][(wr + mi * 16 + r16) * 32 + gr * 8]);
#pragma unroll
    for (int ni = 0; ni < 4; ni++)
      bfr[ni] = *(const bf16x8_t*)(&Bs[cur][(wc + ni * 16 + r16) * 32 + gr * 8]);
    __builtin_amdgcn_s_setprio(1);
#pragma unroll
    for (int mi = 0; mi < 4; mi++)
#pragma unroll
      for (int ni = 0; ni < 4; ni++)
        acc[mi][ni] = __builtin_amdgcn_mfma_f32_16x16x32_bf16(af[mi], bfr[ni], acc[mi][ni], 0, 0, 0);
    __builtin_amdgcn_s_setprio(0);
    if (T + 2 < NT)
      asm volatile("s_waitcnt vmcnt(4)" ::: "memory");
    else
      asm volatile("s_waitcnt vmcnt(0)" ::: "memory");
    __builtin_amdgcn_s_barrier();
  }
#undef STAGE_G

#pragma unroll
  for (int mi = 0; mi < 4; mi++)
#pragma unroll
    for (int ni = 0; ni < 4; ni++) {
      const long rowb = bm + wr + mi * 16 + 4 * g;
      const long colb = bn + wc + ni * 16 + r16;
#pragma unroll
      for (int j = 0; j < 4; j++)
        C[(rowb + j) * N + colb] = acc[mi][ni][j];
    }
}

// ---------- 4. RoPE + scale fold + layout ----------
__global__ void rope_kernel(const float* __restrict__ qkv,
                            const float* __restrict__ sinp,
                            const float* __restrict__ cosp,
                            unsigned short* __restrict__ qr,
                            unsigned short* __restrict__ kr) {
  const int row = blockIdx.x;  // b*2048 + t
  const int b = row >> 11, t = row & 2047;
  const float* src = qkv + (long)row * 2304;
  const int tid = threadIdx.x;
  const int d = tid & 127;
  const int dp = (d + 64) & 127;
  const float c = cosp[t * 128 + d];
  const float s = sinp[t * 128 + d];
  const float sgn = (d < 64) ? -1.f : 1.f;
  for (int h = (tid >> 7); h < 16; h += 2) {
    const float x0 = src[h * 128 + d];
    const float xp = src[h * 128 + dp];
    qr[((long)((b * 16 + h) * 2048 + t)) * 128 + d] = f2bf((x0 * c + sgn * xp * s) * 0.0078125f);
  }
  if (tid < 128) {
    const float x0 = src[2048 + d];
    const float xp = src[2048 + dp];
    kr[((long)(b * 2048 + t)) * 128 + d] = f2bf(x0 * c + sgn * xp * s);
  }
}

// ---------- 5. causal MQA flash attention (v9) ----------
// v8 math (32 q-rows/wave: K/V LDS reads feed TWO q-groups -> traffic per output
// halved) + v7's ROBUST within-block complementary pairing: block processes
// 128-row tile p (2p+2 stages) then tile 15-p (32-2p stages) = uniform 34.
// Grid 256 = 1 block/CU (assignment-proof). launch_bounds(256,1): full VGPR
// budget so the o/qf/sc live set stays in registers.
__global__ __launch_bounds__(256, 1)
void mqa_attn(const unsigned short* __restrict__ qr,
              const unsigned short* __restrict__ kr,
              const unsigned short* __restrict__ vT,
              unsigned short* __restrict__ ao) {
  __shared__ unsigned short Kb[2][64 * 128];   // 2 x 16KB K tiles
  __shared__ unsigned short Vb[128 * 64];      // 16KB V^T tile
  __shared__ unsigned short plds[4][32 * 64];  // per-wave 32x64 P tile (4KB each)
  const int idx = blockIdx.x;  // 256 blocks: pair p (8) x bh (32)
  const int bh = idx & 31, h = bh & 15, b = bh >> 4;
  const int p = idx >> 5;  // 0..7
  const int tid = threadIdx.x;
  const int wid = tid >> 6, lane = tid & 63;
  const int r = lane & 15, g = lane >> 4;
  const int rs = r & 7;
  char* pw = (char*)&plds[wid][0];

  const unsigned short* kbase = kr + (long)b * 2048 * 128;
  const unsigned short* vbase = vT + (long)b * 128 * 2048;
  const unsigned short* qh = qr + (long)(b * 16 + h) * 2048 * 128;

  const int scol = (tid & 15) ^ ((tid >> 4) & 7);  // K staging src granule
  const int vscol = (tid & 7) ^ ((tid >> 3) & 7);  // V staging src granule

  f32x4_t o[2][8];
  float m0, m1, ls0, ls1;
  bf16x8_t qf[2][4];
  int tile = p;
  const int switch_s = 2 * p + 2;

  auto load_q = [&]() {
#pragma unroll
    for (int qg = 0; qg < 2; qg++) {
      const unsigned short* qp = qh + (long)(tile * 128 + wid * 32 + qg * 16 + r) * 128 + g * 8;
#pragma unroll
      for (int c = 0; c < 4; c++) qf[qg][c] = *(const bf16x8_t*)(qp + c * 32);
    }
  };
  auto reset_state = [&]() {
#pragma unroll
    for (int qg = 0; qg < 2; qg++)
#pragma unroll
      for (int i = 0; i < 8; i++) o[qg][i] = (f32x4_t){0.f, 0.f, 0.f, 0.f};
    m0 = m1 = 0.f;
    ls0 = ls1 = 0.f;
  };
  auto flush = [&]() {
#pragma unroll
    for (int qg = 0; qg < 2; qg++) {
      float lt = (qg == 0) ? ls0 : ls1;
      lt += __shfl_xor(lt, 16);
      lt += __shfl_xor(lt, 32);
      float rl[4];
#pragma unroll
      for (int jj = 0; jj < 4; jj++) rl[jj] = 1.0f / __shfl(lt, 4 * g + jj);
      unsigned short* aop =
          ao + ((long)(b * 2048 + tile * 128 + wid * 32 + qg * 16 + 4 * g)) * 2048 + h * 128 + r;
#pragma unroll
      for (int dt = 0; dt < 8; dt++)
#pragma unroll
        for (int jj = 0; jj < 4; jj++)
          aop[(long)jj * 2048 + dt * 16] = f2bf(o[qg][dt][jj] * rl[jj]);
    }
  };

  load_q();
  reset_state();

  // prologue: stage K block 0 into Kb[0]
#pragma unroll
  for (int i = 0; i < 4; i++) {
    const int row = i * 16 + (tid >> 4);
    __builtin_amdgcn_global_load_lds(
        (const AS1 void*)(kbase + (long)row * 128 + scol * 8),
        (AS3 void*)(&Kb[0][(i * 256 + tid) * 8]), 16, 0, 0);
  }
  asm volatile("s_waitcnt vmcnt(0)" ::: "memory");
  __builtin_amdgcn_s_barrier();

  for (int s = 0; s < 34; s++) {
    const int cur = s & 1;
    // tile switch: flush tile A, reload Q, reset running state
    if (s == switch_s) {
      flush();
      tile = 15 - p;
      load_q();
      reset_state();
    }
    const int ss = (s < switch_s) ? s : s - switch_s;  // local stage in current tile
    const int kv0 = 64 * ss;

    // 1. V(ss) staging -> Vb
#pragma unroll
    for (int i = 0; i < 4; i++) {
      const int vrow = i * 32 + (tid >> 3);
      __builtin_amdgcn_global_load_lds(
          (const AS1 void*)(vbase + (long)vrow * 2048 + kv0 + vscol * 8),
          (AS3 void*)(&Vb[(i * 256 + tid) * 8]), 16, 0, 0);
    }
    // 2. K staging for the NEXT stage (crossing the tile boundary restarts at 0)
    const int ns = s + 1;
    if (ns < 34) {
      const int kvn = (ns < switch_s) ? 64 * ns : 64 * (ns - switch_s);
#pragma unroll
      for (int i = 0; i < 4; i++) {
        const int row = i * 16 + (tid >> 4);
        __builtin_amdgcn_global_load_lds(
            (const AS1 void*)(kbase + (long)(kvn + row) * 128 + scol * 8),
            (AS3 void*)(&Kb[cur ^ 1][(i * 256 + tid) * 8]), 16, 0, 0);
      }
    }
    __builtin_amdgcn_sched_barrier(0);

    // 3. QK^T: each kf fragment feeds BOTH q-groups
    f32x4_t sc[2][4];
#pragma unroll
    for (int qg = 0; qg < 2; qg++)
#pragma unroll
      for (int t = 0; t < 4; t++) sc[qg][t] = (f32x4_t){0.f, 0.f, 0.f, 0.f};
    const unsigned short* Kcur = &Kb[cur][0];
    __builtin_amdgcn_s_setprio(1);
#pragma unroll
    for (int t = 0; t < 4; t++) {
      const unsigned short* krow = Kcur + (16 * t + r) * 128;
#pragma unroll
      for (int c = 0; c < 4; c++) {
        const bf16x8_t kf = *(const bf16x8_t*)(krow + (((4 * c + g) ^ rs) << 3));
        sc[0][t] = __builtin_amdgcn_mfma_f32_16x16x32_bf16(kf, qf[0][c], sc[0][t], 0, 0, 0);
        sc[1][t] = __builtin_amdgcn_mfma_f32_16x16x32_bf16(kf, qf[1][c], sc[1][t], 0, 0, 0);
      }
    }
    __builtin_amdgcn_s_setprio(0);

    // 4. causal mask on the current tile's last two stages (kv overlaps own rows)
    if (ss >= 2 * tile) {
      const int sub = ss - 2 * tile;  // 0 or 1
#pragma unroll
      for (int qg = 0; qg < 2; qg++)
#pragma unroll
        for (int t = 0; t < 4; t++)
#pragma unroll
          for (int jj = 0; jj < 4; jj++)
            if (64 * sub + 16 * t + 4 * g + jj > wid * 32 + qg * 16 + r) sc[qg][t][jj] = -1e30f;
    }
    // 5. softmax (defer-max fast path, per q-group state)
    float lm0 = sc[0][0][0], lm1 = sc[1][0][0];
#pragma unroll
    for (int t = 0; t < 4; t++)
#pragma unroll
      for (int jj = 0; jj < 4; jj++) {
        lm0 = fmaxf(lm0, sc[0][t][jj]);
        lm1 = fmaxf(lm1, sc[1][t][jj]);
      }
    if (!__all(lm0 <= m0 + 8.f && lm1 <= m1 + 8.f)) {  // rare rescale path
      float pm0 = lm0, pm1 = lm1;
      pm0 = fmaxf(pm0, __shfl_xor(pm0, 16));
      pm0 = fmaxf(pm0, __shfl_xor(pm0, 32));
      pm1 = fmaxf(pm1, __shfl_xor(pm1, 16));
      pm1 = fmaxf(pm1, __shfl_xor(pm1, 32));
      const float mn0 = fmaxf(m0, pm0), mn1 = fmaxf(m1, pm1);
      const float a0 = __expf(m0 - mn0), a1 = __expf(m1 - mn1);
      ls0 *= a0;
      ls1 *= a1;
      float aj0[4], aj1[4];
#pragma unroll
      for (int jj = 0; jj < 4; jj++) {
        aj0[jj] = __shfl(a0, 4 * g + jj);
        aj1[jj] = __shfl(a1, 4 * g + jj);
      }
#pragma unroll
      for (int dt = 0; dt < 8; dt++)
#pragma unroll
        for (int jj = 0; jj < 4; jj++) {
          o[0][dt][jj] *= aj0[jj];
          o[1][dt][jj] *= aj1[jj];
        }
      m0 = mn0;
      m1 = mn1;
    }
    float p0[16], p1[16];
#pragma unroll
    for (int t = 0; t < 4; t++)
#pragma unroll
      for (int jj = 0; jj < 4; jj++) {
        p0[4 * t + jj] = __expf(sc[0][t][jj] - m0);
        p1[4 * t + jj] = __expf(sc[1][t][jj] - m1);
      }
    float a0 = 0.f, a1 = 0.f;
#pragma unroll
    for (int i = 0; i < 16; i++) {
      a0 += p0[i];
      a1 += p1[i];
    }
    ls0 += a0;
    ls1 += a1;

    // 6. P redistribute through per-wave LDS tile (rows qg*16+r)
    asm volatile("" ::: "memory");
#pragma unroll
    for (int t = 0; t < 4; t++) {
      uint2 w0 = {pack2bf(p0[4 * t], p0[4 * t + 1]), pack2bf(p0[4 * t + 2], p0[4 * t + 3])};
      uint2 w1 = {pack2bf(p1[4 * t], p1[4 * t + 1]), pack2bf(p1[4 * t + 2], p1[4 * t + 3])};
      const int slot = (((2 * t + (g >> 1)) ^ rs) << 4) + ((g & 1) << 3);
      *(uint2*)(pw + r * 128 + slot) = w0;
      *(uint2*)(pw + (16 + r) * 128 + slot) = w1;
    }
    asm volatile("s_waitcnt lgkmcnt(0)" ::: "memory");
    const bf16x8_t pa00 = *(const bf16x8_t*)(pw + r * 128 + ((g ^ rs) << 4));
    const bf16x8_t pa01 = *(const bf16x8_t*)(pw + r * 128 + (((4 + g) ^ rs) << 4));
    const bf16x8_t pa10 = *(const bf16x8_t*)(pw + (16 + r) * 128 + ((g ^ rs) << 4));
    const bf16x8_t pa11 = *(const bf16x8_t*)(pw + (16 + r) * 128 + (((4 + g) ^ rs) << 4));

    // 7. V visibility (K-next still in flight), then barrier
    if (ns < 34)
      asm volatile("s_waitcnt vmcnt(4)" ::: "memory");
    else
      asm volatile("s_waitcnt vmcnt(0)" ::: "memory");
    __builtin_amdgcn_s_barrier();

    // 8. PV from LDS: each vf fragment feeds BOTH q-groups
    __builtin_amdgcn_s_setprio(1);
#pragma unroll
    for (int dt = 0; dt < 8; dt++) {
      const bf16x8_t vfA = *(const bf16x8_t*)(Vb + (dt * 16 + r) * 64 + ((g ^ rs) << 3));
      o[0][dt] = __builtin_amdgcn_mfma_f32_16x16x32_bf16(pa00, vfA, o[0][dt], 0, 0, 0);
      o[1][dt] = __builtin_amdgcn_mfma_f32_16x16x32_bf16(pa10, vfA, o[1][dt], 0, 0, 0);
    }
#pragma unroll
    for (int dt = 0; dt < 8; dt++) {
      const bf16x8_t vfB = *(const bf16x8_t*)(Vb + (dt * 16 + r) * 64 + (((4 + g) ^ rs) << 3));
      o[0][dt] = __builtin_amdgcn_mfma_f32_16x16x32_bf16(pa01, vfB, o[0][dt], 0, 0, 0);
      o[1][dt] = __builtin_amdgcn_mfma_f32_16x16x32_bf16(pa11, vfB, o[1][dt], 0, 0, 0);
    }
    __builtin_amdgcn_s_setprio(0);

    // 9. drain K staging + sync
    asm volatile("s_waitcnt vmcnt(0)" ::: "memory");
    __builtin_amdgcn_s_barrier();
  }
  flush();  // tile B
}

extern "C" void kernel_launch(void* const* d_in, const int* in_sizes, int n_in,
                              void* d_out, int out_size, void* d_ws, size_t ws_size,
                              hipStream_t stream) {
  const float* x    = (const float*)d_in[0];
  const float* sinp = (const float*)d_in[1];
  const float* cosp = (const float*)d_in[2];
  const float* Wqkv = (const float*)d_in[3];
  const float* Wo   = (const float*)d_in[4];
  float* out = (float*)d_out;
  char* ws = (char*)d_ws;

  const int B = 2, T = 2048, D = 2048, H = 16, HD = 128;
  const int M = B * T;        // 4096
  const int NQ = D + 2 * HD;  // 2304

  unsigned short* xb    = (unsigned short*)(ws + 0);         // 16,777,216
  unsigned short* wqkvT = (unsigned short*)(ws + 16777216);  //  9,437,184
  unsigned short* woT   = (unsigned short*)(ws + 26214400);  //  8,388,608
  float*          qkv   = (float*)         (ws + 34603008);  // 37,748,736
  unsigned short* qr    = (unsigned short*)(ws + 72351744);  // 16,777,216
  unsigned short* kr    = (unsigned short*)(ws + 89128960);  //  1,048,576
  unsigned short* vT    = (unsigned short*)(ws + 90177536);  //  1,048,576
  unsigned short* ao    = xb;  // reuse xb after first GEMM

  dim3 tb(64, 4);
  cvt_bf16_kernel<<<(M * D) / 1024, 256, 0, stream>>>(x, xb);
  transpose_f32_bf16<<<dim3(NQ / 64, D / 64, 1), tb, 0, stream>>>(Wqkv, wqkvT, NQ, D, 0, 0);
  transpose_f32_bf16<<<dim3(D / 64, D / 64, 1), tb, 0, stream>>>(Wo, woT, D, D, 0, 0);
  gemm_bt<<<dim3((NQ / 128) * (M / 128)), 256, 0, stream>>>(xb, wqkvT, qkv, M, NQ, D, NQ / 128);
  rope_kernel<<<M, 256, 0, stream>>>(qkv, sinp, cosp, qr, kr);
  transpose_f32_bf16<<<dim3(HD / 64, T / 64, B), tb, 0, stream>>>(
      qkv + 2176, vT, NQ, T, (long)T * NQ, (long)HD * T);
  mqa_attn<<<dim3(256), 256, 0, stream>>>(qr, kr, vT, ao);
  gemm_bt<<<dim3((D / 128) * (M / 128)), 256, 0, stream>>>(ao, woT, out, M, D, D, D / 128);
}

// Round 12
// 202.865 us; speedup vs baseline: 1.1091x; 1.1091x over previous
//
#include <hip/hip_runtime.h>
#include <stdint.h>

typedef __bf16 bf16x8_t __attribute__((ext_vector_type(8)));
typedef float f32x4_t __attribute__((ext_vector_type(4)));

#define AS1 __attribute__((address_space(1)))
#define AS3 __attribute__((address_space(3)))

static __device__ __forceinline__ unsigned short f2bf(float f) {
  union { float f; unsigned u; } a;
  a.f = f;
  unsigned r = a.u + 0x7fffu + ((a.u >> 16) & 1u);
  return (unsigned short)(r >> 16);
}

// HW packed f32x2 -> bf16x2 (RNE) — T12 recipe
static __device__ __forceinline__ unsigned cvtpk(float lo, float hi) {
  unsigned r;
  asm("v_cvt_pk_bf16_f32 %0, %1, %2" : "=v"(r) : "v"(lo), "v"(hi));
  return r;
}

// ---------- 1. fp32 -> bf16 elementwise ----------
__global__ void cvt_bf16_kernel(const float* __restrict__ in, unsigned short* __restrict__ out) {
  long i = ((long)blockIdx.x * blockDim.x + threadIdx.x) * 4;
  float4 v = *(const float4*)(in + i);
  ushort4 o;
  o.x = f2bf(v.x);
  o.y = f2bf(v.y);
  o.z = f2bf(v.z);
  o.w = f2bf(v.w);
  *(ushort4*)(out + i) = o;
}

// ---------- 2. fp32 [R][C] (row stride ld) -> bf16 [C][R] (row stride dld) ----------
__global__ void transpose_f32_bf16(const float* __restrict__ src, unsigned short* __restrict__ dst,
                                   int ld, int dld, long sbs, long dbs) {
  __shared__ float tile[64][65];
  src += (long)blockIdx.z * sbs;
  dst += (long)blockIdx.z * dbs;
  const int c0 = blockIdx.x * 64, r0 = blockIdx.y * 64;
  const int tx = threadIdx.x, ty = threadIdx.y;
#pragma unroll
  for (int j = 0; j < 64; j += 4)
    tile[ty + j][tx] = src[(long)(r0 + ty + j) * ld + (c0 + tx)];
  __syncthreads();
#pragma unroll
  for (int j = 0; j < 64; j += 4)
    dst[(long)(c0 + ty + j) * dld + (r0 + tx)] = f2bf(tile[tx][ty + j]);
}

// ---------- 3. GEMM (round-9 pipeline: 3-buf LDS, counted vmcnt, slot swizzle) ----------
__global__ __launch_bounds__(256) void gemm_bt(const unsigned short* __restrict__ A,
                                               const unsigned short* __restrict__ Bt,
                                               float* __restrict__ C,
                                               int M, int N, int K, int nx) {
  __shared__ unsigned short As[3][128 * 32];
  __shared__ unsigned short Bs[3][128 * 32];
  const int nwg = gridDim.x;
  const int bid = blockIdx.x;
  const int swz = (bid & 7) * (nwg >> 3) + (bid >> 3);  // XCD chunking
  const int by = swz / nx;
  const int bx = swz - by * nx;

  const int tid = threadIdx.x;
  const int wid = tid >> 6, lane = tid & 63;
  const int r16 = lane & 15, g = lane >> 4;
  const long bm = (long)by * 128;
  const long bn = (long)bx * 128;
  const int wr = (wid >> 1) * 64, wc = (wid & 1) * 64;
  const int gr = g ^ (r16 & 3);
  const int sslot = (lane & 3) ^ ((lane >> 2) & 3);

  f32x4_t acc[4][4];
#pragma unroll
  for (int i = 0; i < 4; i++)
#pragma unroll
    for (int j = 0; j < 4; j++) acc[i][j] = (f32x4_t){0.f, 0.f, 0.f, 0.f};

  const int NT = K >> 5;

#define STAGE_G(buf, kt)                                                              \
  {                                                                                   \
    _Pragma("unroll") for (int i = 0; i < 2; i++) {                                   \
      const int chunk = (i * 4 + wid) * 64 + lane;                                    \
      const int row = chunk >> 2;                                                     \
      __builtin_amdgcn_global_load_lds(                                               \
          (const AS1 void*)(A + (bm + row) * K + (kt) + sslot * 8),                   \
          (AS3 void*)(&As[buf][chunk * 8]), 16, 0, 0);                                \
      __builtin_amdgcn_global_load_lds(                                               \
          (const AS1 void*)(Bt + (bn + row) * K + (kt) + sslot * 8),                  \
          (AS3 void*)(&Bs[buf][chunk * 8]), 16, 0, 0);                                \
    }                                                                                 \
  }

  STAGE_G(0, 0)
  STAGE_G(1, 32)
  asm volatile("s_waitcnt vmcnt(4)" ::: "memory");
  __builtin_amdgcn_s_barrier();

  for (int T = 0; T < NT; T++) {
    const int cur = T % 3;
    if (T + 2 < NT) {
      const int nb = (T + 2) % 3;
      STAGE_G(nb, (T + 2) * 32)
    }
    __builtin_amdgcn_sched_barrier(0);
    bf16x8_t af[4], bfr[4];
#pragma unroll
    for (int mi = 0; mi < 4; mi++)
      af[mi] = *(const bf16x8_t*)(&As[cur][(wr + mi * 16 + r16) * 32 + gr * 8]);
#pragma unroll
    for (int ni = 0; ni < 4; ni++)
      bfr[ni] = *(const bf16x8_t*)(&Bs[cur][(wc + ni * 16 + r16) * 32 + gr * 8]);
    __builtin_amdgcn_s_setprio(1);
#pragma unroll
    for (int mi = 0; mi < 4; mi++)
#pragma unroll
      for (int ni = 0; ni < 4; ni++)
        acc[mi][ni] = __builtin_amdgcn_mfma_f32_16x16x32_bf16(af[mi], bfr[ni], acc[mi][ni], 0, 0, 0);
    __builtin_amdgcn_s_setprio(0);
    if (T + 2 < NT)
      asm volatile("s_waitcnt vmcnt(4)" ::: "memory");
    else
      asm volatile("s_waitcnt vmcnt(0)" ::: "memory");
    __builtin_amdgcn_s_barrier();
  }
#undef STAGE_G

#pragma unroll
  for (int mi = 0; mi < 4; mi++)
#pragma unroll
    for (int ni = 0; ni < 4; ni++) {
      const long rowb = bm + wr + mi * 16 + 4 * g;
      const long colb = bn + wc + ni * 16 + r16;
#pragma unroll
      for (int j = 0; j < 4; j++)
        C[(rowb + j) * N + colb] = acc[mi][ni][j];
    }
}

// ---------- 4. RoPE + scale fold + layout ----------
// q scale = 1/128 * log2(e): attention softmax runs in exp2 domain (saves a
// v_mul per score; v_exp_f32 IS exp2).
__global__ void rope_kernel(const float* __restrict__ qkv,
                            const float* __restrict__ sinp,
                            const float* __restrict__ cosp,
                            unsigned short* __restrict__ qr,
                            unsigned short* __restrict__ kr) {
  const int row = blockIdx.x;  // b*2048 + t
  const int b = row >> 11, t = row & 2047;
  const float* src = qkv + (long)row * 2304;
  const int tid = threadIdx.x;
  const int d = tid & 127;
  const int dp = (d + 64) & 127;
  const float c = cosp[t * 128 + d];
  const float s = sinp[t * 128 + d];
  const float sgn = (d < 64) ? -1.f : 1.f;
  for (int h = (tid >> 7); h < 16; h += 2) {
    const float x0 = src[h * 128 + d];
    const float xp = src[h * 128 + dp];
    qr[((long)((b * 16 + h) * 2048 + t)) * 128 + d] =
        f2bf((x0 * c + sgn * xp * s) * 0.011271055f);
  }
  if (tid < 128) {
    const float x0 = src[2048 + d];
    const float xp = src[2048 + dp];
    kr[((long)(b * 2048 + t)) * 128 + d] = f2bf(x0 * c + sgn * xp * s);
  }
}

// ---------- 5. causal MQA flash attention (v10 = v7 + V-dbuf + exp2 + cvt_pk) ----------
// 512 blocks (tile pj then 31-pj, uniform 33 stages), 16 q-rows/wave.
// K AND V double-buffered in LDS (72KB, 2 blocks/CU). Per stage: issue
// K(s+1) then V(s+1) -> QK -> softmax(exp2) -> P-LDS -> vmcnt(8)+barrier
// (V(s) had a FULL stage to land; K/V(s+1) stay in flight) -> PV ->
// vmcnt(4)+barrier (K(s+1) landed, V(s+1) still flying).
__global__ __launch_bounds__(256, 2)
void mqa_attn(const unsigned short* __restrict__ qr,
              const unsigned short* __restrict__ kr,
              const unsigned short* __restrict__ vT,
              unsigned short* __restrict__ ao) {
  __shared__ unsigned short Kb[2][64 * 128];   // 2 x 16KB K tiles
  __shared__ unsigned short Vb[2][128 * 64];   // 2 x 16KB V^T tiles
  __shared__ unsigned short plds[4][16 * 64];  // per-wave P tile (2KB each)
  const int idx = blockIdx.x;  // 512 blocks
  const int pj = idx & 15, h = (idx >> 4) & 15, b = idx >> 8;
  const int tid = threadIdx.x;
  const int wid = tid >> 6, lane = tid & 63;
  const int r = lane & 15, g = lane >> 4;
  const int rs = r & 7;
  char* pw = (char*)&plds[wid][0];

  const unsigned short* kbase = kr + (long)b * 2048 * 128;
  const unsigned short* vbase = vT + (long)b * 128 * 2048;
  const unsigned short* qh = qr + (long)(b * 16 + h) * 2048 * 128;

  const int scol = (tid & 15) ^ ((tid >> 4) & 7);  // K staging src granule
  const int vscol = (tid & 7) ^ ((tid >> 3) & 7);  // V staging src granule

  f32x4_t o[8];
#pragma unroll
  for (int i = 0; i < 8; i++) o[i] = (f32x4_t){0.f, 0.f, 0.f, 0.f};
  float m = 0.f, lsum = 0.f;

  int tile = pj;
  bf16x8_t qf[4];
  {
    const unsigned short* qp = qh + (long)(tile * 64 + wid * 16 + r) * 128 + g * 8;
#pragma unroll
    for (int c = 0; c < 4; c++) qf[c] = *(const bf16x8_t*)(qp + c * 32);
  }

  // prologue: stage K(0) -> Kb[0], V(0) -> Vb[0]
#pragma unroll
  for (int i = 0; i < 4; i++) {
    const int row = i * 16 + (tid >> 4);
    __builtin_amdgcn_global_load_lds(
        (const AS1 void*)(kbase + (long)row * 128 + scol * 8),
        (AS3 void*)(&Kb[0][(i * 256 + tid) * 8]), 16, 0, 0);
  }
#pragma unroll
  for (int i = 0; i < 4; i++) {
    const int vrow = i * 32 + (tid >> 3);
    __builtin_amdgcn_global_load_lds(
        (const AS1 void*)(vbase + (long)vrow * 2048 + vscol * 8),
        (AS3 void*)(&Vb[0][(i * 256 + tid) * 8]), 16, 0, 0);
  }
  asm volatile("s_waitcnt vmcnt(0)" ::: "memory");
  __builtin_amdgcn_s_barrier();

  const int switch_s = pj + 1;
  for (int s = 0; s <= 32; s++) {
    const int cur = s & 1;

    // 0. tile switch: flush tile A (O stores + Q reload) at stage top
    if (s == switch_s) {
      float lt = lsum;
      lt += __shfl_xor(lt, 16);
      lt += __shfl_xor(lt, 32);
      float rl[4];
#pragma unroll
      for (int jj = 0; jj < 4; jj++) rl[jj] = 1.0f / __shfl(lt, 4 * g + jj);
      unsigned short* aop = ao + ((long)(b * 2048 + tile * 64 + wid * 16 + 4 * g)) * 2048 + h * 128 + r;
#pragma unroll
      for (int dt = 0; dt < 8; dt++)
#pragma unroll
        for (int jj = 0; jj < 4; jj++)
          aop[(long)jj * 2048 + dt * 16] = f2bf(o[dt][jj] * rl[jj]);
      tile = 31 - pj;
      const unsigned short* qp = qh + (long)(tile * 64 + wid * 16 + r) * 128 + g * 8;
#pragma unroll
      for (int c = 0; c < 4; c++) qf[c] = *(const bf16x8_t*)(qp + c * 32);
#pragma unroll
      for (int i = 0; i < 8; i++) o[i] = (f32x4_t){0.f, 0.f, 0.f, 0.f};
      m = 0.f;
      lsum = 0.f;
    }

    // 1. staging for NEXT stage: K(s+1) first, then V(s+1) (order matters for
    //    the counted waits below)
    if (s < 32) {
      const int kvn = (s + 1 <= pj) ? 64 * (s + 1) : 64 * (s - pj);
#pragma unroll
      for (int i = 0; i < 4; i++) {
        const int row = i * 16 + (tid >> 4);
        __builtin_amdgcn_global_load_lds(
            (const AS1 void*)(kbase + (long)(kvn + row) * 128 + scol * 8),
            (AS3 void*)(&Kb[cur ^ 1][(i * 256 + tid) * 8]), 16, 0, 0);
      }
      __builtin_amdgcn_sched_barrier(0);
#pragma unroll
      for (int i = 0; i < 4; i++) {
        const int vrow = i * 32 + (tid >> 3);
        __builtin_amdgcn_global_load_lds(
            (const AS1 void*)(vbase + (long)vrow * 2048 + kvn + vscol * 8),
            (AS3 void*)(&Vb[cur ^ 1][(i * 256 + tid) * 8]), 16, 0, 0);
      }
    }
    __builtin_amdgcn_sched_barrier(0);

    // 2. QK^T from LDS K tile
    f32x4_t sc[4];
#pragma unroll
    for (int t = 0; t < 4; t++) sc[t] = (f32x4_t){0.f, 0.f, 0.f, 0.f};
    const unsigned short* Kcur = &Kb[cur][0];
    __builtin_amdgcn_s_setprio(1);
#pragma unroll
    for (int t = 0; t < 4; t++) {
      const unsigned short* krow = Kcur + (16 * t + r) * 128;
#pragma unroll
      for (int c = 0; c < 4; c++) {
        const bf16x8_t kf = *(const bf16x8_t*)(krow + (((4 * c + g) ^ rs) << 3));
        sc[t] = __builtin_amdgcn_mfma_f32_16x16x32_bf16(kf, qf[c], sc[t], 0, 0, 0);
      }
    }
    __builtin_amdgcn_s_setprio(0);

    // 3. causal mask on the current tile's last stage
    if (s == pj || s == 32) {
#pragma unroll
      for (int t = 0; t < 4; t++)
#pragma unroll
        for (int jj = 0; jj < 4; jj++)
          if (t * 16 + 4 * g + jj > wid * 16 + r) sc[t][jj] = -1e30f;
    }
    // 4. softmax in exp2 domain (defer-max fast path), fmax TREE not chain
    float mx01 = fmaxf(fmaxf(sc[0][0], sc[0][1]), fmaxf(sc[0][2], sc[0][3]));
    float mx23 = fmaxf(fmaxf(sc[1][0], sc[1][1]), fmaxf(sc[1][2], sc[1][3]));
    float mx45 = fmaxf(fmaxf(sc[2][0], sc[2][1]), fmaxf(sc[2][2], sc[2][3]));
    float mx67 = fmaxf(fmaxf(sc[3][0], sc[3][1]), fmaxf(sc[3][2], sc[3][3]));
    const float lm = fmaxf(fmaxf(mx01, mx23), fmaxf(mx45, mx67));
    if (!__all(lm <= m + 11.5f)) {  // rare rescale path (11.5 bits ~ 8 nats)
      float pm = lm;
      pm = fmaxf(pm, __shfl_xor(pm, 16));
      pm = fmaxf(pm, __shfl_xor(pm, 32));
      const float mnew = fmaxf(m, pm);
      const float alpha = __builtin_amdgcn_exp2f(m - mnew);
      lsum *= alpha;
      float aj[4];
#pragma unroll
      for (int jj = 0; jj < 4; jj++) aj[jj] = __shfl(alpha, 4 * g + jj);
#pragma unroll
      for (int dt = 0; dt < 8; dt++) {
        o[dt][0] *= aj[0]; o[dt][1] *= aj[1]; o[dt][2] *= aj[2]; o[dt][3] *= aj[3];
      }
      m = mnew;
    }
    float p[16];
#pragma unroll
    for (int t = 0; t < 4; t++)
#pragma unroll
      for (int jj = 0; jj < 4; jj++) p[4 * t + jj] = __builtin_amdgcn_exp2f(sc[t][jj] - m);
    float ls = 0.f;
#pragma unroll
    for (int i = 0; i < 16; i++) ls += p[i];
    lsum += ls;

    // 5. P redistribute through per-wave LDS tile (HW cvt_pk packing)
    asm volatile("" ::: "memory");
#pragma unroll
    for (int t = 0; t < 4; t++) {
      uint2 w = {cvtpk(p[4 * t], p[4 * t + 1]), cvtpk(p[4 * t + 2], p[4 * t + 3])};
      *(uint2*)(pw + r * 128 + (((2 * t + (g >> 1)) ^ rs) << 4) + ((g & 1) << 3)) = w;
    }
    asm volatile("s_waitcnt lgkmcnt(0)" ::: "memory");
    const bf16x8_t pa0 = *(const bf16x8_t*)(pw + r * 128 + ((g ^ rs) << 4));
    const bf16x8_t pa1 = *(const bf16x8_t*)(pw + r * 128 + (((4 + g) ^ rs) << 4));

    // 6. V(s) visibility: V(s) staged a FULL stage ago; only K/V(s+1) (8 instrs)
    //    are newer -> vmcnt(8) is satisfied ~immediately. Barrier for cross-wave.
    if (s < 32)
      asm volatile("s_waitcnt vmcnt(8)" ::: "memory");
    else
      asm volatile("s_waitcnt vmcnt(0)" ::: "memory");
    __builtin_amdgcn_s_barrier();

    // 7. PV from LDS V tile
    const unsigned short* Vcur = &Vb[cur][0];
    __builtin_amdgcn_s_setprio(1);
#pragma unroll
    for (int dt = 0; dt < 8; dt++) {
      const bf16x8_t vfA = *(const bf16x8_t*)(Vcur + (dt * 16 + r) * 64 + ((g ^ rs) << 3));
      o[dt] = __builtin_amdgcn_mfma_f32_16x16x32_bf16(pa0, vfA, o[dt], 0, 0, 0);
    }
#pragma unroll
    for (int dt = 0; dt < 8; dt++) {
      const bf16x8_t vfB = *(const bf16x8_t*)(Vcur + (dt * 16 + r) * 64 + (((4 + g) ^ rs) << 3));
      o[dt] = __builtin_amdgcn_mfma_f32_16x16x32_bf16(pa1, vfB, o[dt], 0, 0, 0);
    }
    __builtin_amdgcn_s_setprio(0);

    // 8. end: K(s+1) landed (V(s+1) may still fly) -> next stage QK safe
    if (s < 32)
      asm volatile("s_waitcnt vmcnt(4)" ::: "memory");
    else
      asm volatile("s_waitcnt vmcnt(0)" ::: "memory");
    __builtin_amdgcn_s_barrier();
  }
  // epilogue: flush tile B
  {
    float lt = lsum;
    lt += __shfl_xor(lt, 16);
    lt += __shfl_xor(lt, 32);
    float rl[4];
#pragma unroll
    for (int jj = 0; jj < 4; jj++) rl[jj] = 1.0f / __shfl(lt, 4 * g + jj);
    unsigned short* aop = ao + ((long)(b * 2048 + tile * 64 + wid * 16 + 4 * g)) * 2048 + h * 128 + r;
#pragma unroll
    for (int dt = 0; dt < 8; dt++)
#pragma unroll
      for (int jj = 0; jj < 4; jj++)
        aop[(long)jj * 2048 + dt * 16] = f2bf(o[dt][jj] * rl[jj]);
  }
}

extern "C" void kernel_launch(void* const* d_in, const int* in_sizes, int n_in,
                              void* d_out, int out_size, void* d_ws, size_t ws_size,
                              hipStream_t stream) {
  const float* x    = (const float*)d_in[0];
  const float* sinp = (const float*)d_in[1];
  const float* cosp = (const float*)d_in[2];
  const float* Wqkv = (const float*)d_in[3];
  const float* Wo   = (const float*)d_in[4];
  float* out = (float*)d_out;
  char* ws = (char*)d_ws;

  const int B = 2, T = 2048, D = 2048, H = 16, HD = 128;
  const int M = B * T;        // 4096
  const int NQ = D + 2 * HD;  // 2304

  unsigned short* xb    = (unsigned short*)(ws + 0);         // 16,777,216
  unsigned short* wqkvT = (unsigned short*)(ws + 16777216);  //  9,437,184
  unsigned short* woT   = (unsigned short*)(ws + 26214400);  //  8,388,608
  float*          qkv   = (float*)         (ws + 34603008);  // 37,748,736
  unsigned short* qr    = (unsigned short*)(ws + 72351744);  // 16,777,216
  unsigned short* kr    = (unsigned short*)(ws + 89128960);  //  1,048,576
  unsigned short* vT    = (unsigned short*)(ws + 90177536);  //  1,048,576
  unsigned short* ao    = xb;  // reuse xb after first GEMM

  dim3 tb(64, 4);
  cvt_bf16_kernel<<<(M * D) / 1024, 256, 0, stream>>>(x, xb);
  transpose_f32_bf16<<<dim3(NQ / 64, D / 64, 1), tb, 0, stream>>>(Wqkv, wqkvT, NQ, D, 0, 0);
  transpose_f32_bf16<<<dim3(D / 64, D / 64, 1), tb, 0, stream>>>(Wo, woT, D, D, 0, 0);
  gemm_bt<<<dim3((NQ / 128) * (M / 128)), 256, 0, stream>>>(xb, wqkvT, qkv, M, NQ, D, NQ / 128);
  rope_kernel<<<M, 256, 0, stream>>>(qkv, sinp, cosp, qr, kr);
  transpose_f32_bf16<<<dim3(HD / 64, T / 64, B), tb, 0, stream>>>(
      qkv + 2176, vT, NQ, T, (long)T * NQ, (long)HD * T);
  mqa_attn<<<dim3(512), 256, 0, stream>>>(qr, kr, vT, ao);
  gemm_bt<<<dim3((D / 128) * (M / 128)), 256, 0, stream>>>(ao, woT, out, M, D, D, D / 128);
}